// Round 8
// baseline (98.775 us; speedup 1.0000x reference)
//
#include <hip/hip_runtime.h>
#include <hip/hip_bf16.h>
#include <math.h>

typedef __attribute__((ext_vector_type(8))) short bf16x8;
typedef __attribute__((ext_vector_type(8))) unsigned short u16x8;
typedef __attribute__((ext_vector_type(4))) float f32x4;
typedef __attribute__((ext_vector_type(16))) float f32x16;

__device__ __forceinline__ unsigned short f2bf(float f) {
  unsigned u = __float_as_uint(f);
  return (unsigned short)((u + 0x7FFFu + ((u >> 16) & 1u)) >> 16);
}
__device__ __forceinline__ float bf2f(unsigned short h) {
  return __uint_as_float(((unsigned)h) << 16);
}
// fp32x8 -> bf16 hi/lo split via packed cvt (compiler emits v_cvt_pk_bf16_f32)
__device__ __forceinline__ void cvt8pk(const float4& a, const float4& b,
                                       u16x8& h, u16x8& l) {
  float f[8] = {a.x, a.y, a.z, a.w, b.x, b.y, b.z, b.w};
  unsigned* hp = (unsigned*)&h;
  unsigned* lp = (unsigned*)&l;
#pragma unroll
  for (int i = 0; i < 4; ++i) {
    __hip_bfloat162 hb = __float22bfloat162_rn(make_float2(f[2*i], f[2*i+1]));
    unsigned hv = *(unsigned*)&hb;
    hp[i] = hv;
    float r0 = f[2*i]     - __uint_as_float(hv << 16);
    float r1 = f[2*i + 1] - __uint_as_float(hv & 0xFFFF0000u);
    __hip_bfloat162 lb = __float22bfloat162_rn(make_float2(r0, r1));
    lp[i] = *(unsigned*)&lb;
  }
}
__device__ __forceinline__ void cvt8b(const float4& a, const float4& b,
                                      bf16x8& h, bf16x8& l) {
  u16x8 hh, ll;
  cvt8pk(a, b, hh, ll);
  h = *(bf16x8*)&hh;
  l = *(bf16x8*)&ll;
}

#define GLD16(g, l) __builtin_amdgcn_global_load_lds( \
    (const __attribute__((address_space(1))) void*)(g), \
    (__attribute__((address_space(3))) void*)(l), 16, 0, 0)

#define MFMA32(a, b, c) __builtin_amdgcn_mfma_f32_32x32x16_bf16(a, b, c, 0, 0, 0)

// pair tables: 36 (m,n) pairs with m<=n
__device__ const int PM36[36] = {0,0,0,0,0,0,0,0, 1,1,1,1,1,1,1, 2,2,2,2,2,2,
                                 3,3,3,3,3, 4,4,4,4, 5,5,5, 6,6, 7};
__device__ const int PN36[36] = {0,1,2,3,4,5,6,7, 1,2,3,4,5,6,7, 2,3,4,5,6,7,
                                 3,4,5,6,7, 4,5,6,7, 5,6,7, 6,7, 7};
__device__ __forceinline__ constexpr int gidx(int a, int b) {
  int m = a < b ? a : b, n = a < b ? b : a;
  return m * 8 - (m * (m - 1)) / 2 + (n - m);
}

// ---------------------------------------------------------------------------
// K0 (merged): blocks 0-15: split/transpose Wp -> th1/tl1 [kt16][ks8][col128][e8]
//              blocks 16-31: split Wflat -> th2/tl2 [kt2][ks8][col512][e8]
//              blocks 32-95: Gram M[a][b] = Wf[a]·Wf[b]
// ---------------------------------------------------------------------------
__global__ __launch_bounds__(256) void caps_prep_all(
    const float* __restrict__ Wp, const float* __restrict__ W,
    unsigned short* __restrict__ th1, unsigned short* __restrict__ tl1,
    unsigned short* __restrict__ th2, unsigned short* __restrict__ tl2,
    float* __restrict__ M)
{
  __shared__ float tile[64][128];
  const int t = threadIdx.x, b = blockIdx.x;
  if (b < 16) {
    const float* src = Wp + (size_t)b * 64 * 128;
#pragma unroll
    for (int i = 0; i < 8; ++i) {
      int j = t + i * 256;
      int kk = j >> 5, q = j & 31;
      *(float4*)&tile[kk][q * 4] = *(const float4*)(src + kk * 128 + q * 4);
    }
    __syncthreads();
    const int col = t >> 1, kg0 = (t & 1) * 4;
    unsigned short hi[32], lo[32];
#pragma unroll
    for (int kk = 0; kk < 32; ++kk) {
      float v = tile[kg0 * 8 + kk][col];
      unsigned short h = f2bf(v);
      hi[kk] = h;
      lo[kk] = f2bf(v - bf2f(h));
    }
#pragma unroll
    for (int i = 0; i < 4; ++i) {
      size_t off = (size_t)b * 8192 + (size_t)(kg0 + i) * 1024 + (size_t)col * 8;
      u16x8 vh, vl;
#pragma unroll
      for (int e = 0; e < 8; ++e) { vh[e] = hi[i * 8 + e]; vl[e] = lo[i * 8 + e]; }
      *(u16x8*)(th1 + off) = vh;
      *(u16x8*)(tl1 + off) = vl;
    }
  } else if (b < 32) {
    int tt = (b - 16) * 256 + t;
#pragma unroll
    for (int h = 0; h < 2; ++h) {
      int c = tt + h * 4096;
      int kt = c >> 12, rem = c & 4095;
      int kg = rem >> 9, col = rem & 511;
      int kbase = kt * 64 + kg * 8;
      u16x8 vh, vl;
#pragma unroll
      for (int e = 0; e < 8; ++e) {
        float v = W[(size_t)(kbase + e) * 512 + col];
        unsigned short hh = f2bf(v);
        vh[e] = hh;
        vl[e] = f2bf(v - bf2f(hh));
      }
      size_t off = ((size_t)(kt * 8 + kg) * 512 + col) * 8;
      *(u16x8*)(th2 + off) = vh;
      *(u16x8*)(tl2 + off) = vl;
    }
  } else {
    int bb = b - 32;
    int a = (bb >> 3) * 16 + (t >> 4);
    int c = (bb & 7) * 16 + (t & 15);
    const float* wa = W + (size_t)a * 512;
    const float* wb = W + (size_t)c * 512;
    float acc = 0.f;
#pragma unroll 4
    for (int o = 0; o < 512; o += 4) {
      float4 xx = *(const float4*)(wa + o);
      float4 yy = *(const float4*)(wb + o);
      acc += xx.x * yy.x + xx.y * yy.y + xx.z * yy.z + xx.w * yy.w;
    }
    M[a * 128 + c] = acc;
  }
}

// ---------------------------------------------------------------------------
// K1: p = squash(x @ Wp + bp), split-bf16 via 32x32x16 MFMA.
// BM=32, BN=128, BK=64, 256 thr (4 waves, wave wn -> cols wn*32..+31),
// grid 512 -> 2 blocks/CU. LDS dbuf 2x40KB = 80KB:
//   per buf (shorts): A_hi[ks8][row32][e8] @0, A_lo @2048,
//                     B_hi[ks8][col128][e8] @4096, B_lo @12288.
// B staged via global_load_lds (pre-split); A reg-staged + pk-cvt.
// Per K-step per wave: 12 MFMA(32x32x16), 16 ds_read_b128.
// ---------------------------------------------------------------------------
#define K1BUF 20480   // shorts per buffer (40 KB)

__global__ __launch_bounds__(256) void caps_primary(
    const float* __restrict__ x, const unsigned short* __restrict__ bth,
    const unsigned short* __restrict__ btl, const float* __restrict__ bp,
    float* __restrict__ p_out)
{
  __shared__ unsigned short lds[2 * K1BUF];   // 80 KB
  const int tid  = threadIdx.x;
  const int lane = tid & 63;
  const int wn   = tid >> 6;       // 0..3 -> cols wn*32..+31
  const int lc   = lane & 31;
  const int hi   = lane >> 5;
  const int row0 = blockIdx.x * 32;

  const int rowA = tid & 31;       // A staging: (row=rowA, ks=kgA)
  const int kgA  = tid >> 5;       // 0..7
  const float* xrow = x + (size_t)(row0 + rowA) * 1024 + kgA * 8;

  f32x16 acc;
#pragma unroll
  for (int j = 0; j < 16; ++j) acc[j] = 0.f;

  float4 a0, a1;

#define A_LOAD(kt) do { const float* xp_ = xrow + (kt) * 64; \
    a0 = *(const float4*)(xp_); a1 = *(const float4*)(xp_ + 4); } while (0)

#define B_ISSUE(kt, bufi) do { \
    unsigned short* Bh_ = lds + (bufi) * K1BUF + 4096; \
    unsigned short* Bl_ = lds + (bufi) * K1BUF + 12288; \
    const unsigned short* gh_ = bth + ((size_t)(kt) * 1024 + tid) * 8; \
    const unsigned short* gl_ = btl + ((size_t)(kt) * 1024 + tid) * 8; \
    _Pragma("unroll") for (int c_ = 0; c_ < 4; ++c_) { \
      GLD16(gh_ + c_ * 2048, Bh_ + (c_ * 256 + tid) * 8); \
      GLD16(gl_ + c_ * 2048, Bl_ + (c_ * 256 + tid) * 8); \
    } } while (0)

#define A_WRITE(bufi) do { u16x8 h_, l_; cvt8pk(a0, a1, h_, l_); \
    unsigned short* A_ = lds + (bufi) * K1BUF; \
    *(u16x8*)(A_ + (kgA * 32 + rowA) * 8) = h_; \
    *(u16x8*)(A_ + 2048 + (kgA * 32 + rowA) * 8) = l_; } while (0)

#define COMPUTE(bufi) do { \
    const unsigned short* F = lds + (bufi) * K1BUF; \
    _Pragma("unroll") \
    for (int kk = 0; kk < 4; ++kk) { \
      const int ks = kk * 2 + hi; \
      bf16x8 ah  = *(const bf16x8*)(F + (ks * 32 + lc) * 8); \
      bf16x8 al  = *(const bf16x8*)(F + 2048 + (ks * 32 + lc) * 8); \
      bf16x8 bh  = *(const bf16x8*)(F + 4096  + (ks * 128 + wn * 32 + lc) * 8); \
      bf16x8 blo = *(const bf16x8*)(F + 12288 + (ks * 128 + wn * 32 + lc) * 8); \
      acc = MFMA32(ah, bh,  acc); \
      acc = MFMA32(ah, blo, acc); \
      acc = MFMA32(al, bh,  acc); \
    } } while (0)

  // prologue
  A_LOAD(0);
  B_ISSUE(0, 0);
  A_WRITE(0);
  __syncthreads();

#pragma unroll 2
  for (int kt = 0; kt < 16; ++kt) {
    const int cur = kt & 1;
    if (kt < 15) {
      A_LOAD(kt + 1);           // global->reg (A), issued first
      B_ISSUE(kt + 1, cur ^ 1); // global->LDS async (B)
    }
    COMPUTE(cur);
    if (kt < 15) A_WRITE(cur ^ 1);
    __syncthreads();
  }
#undef A_LOAD
#undef B_ISSUE
#undef A_WRITE
#undef COMPUTE

  // epilogue: bias + per-capsule squash.
  // C/D 32x32: col = wn*32 + lc, row = (r&3) + 8*(r>>2) + 4*hi.
  // capsule = 16 consecutive cols -> reduce across 16-lane quarter (xor 1,2,4,8).
  const int col = wn * 32 + lc;
  const float bpv = bp[col];
#pragma unroll
  for (int r = 0; r < 16; ++r) {
    const int row = (r & 3) + 8 * (r >> 2) + 4 * hi;
    float val = acc[r] + bpv;
    float sq = val * val;
    sq += __shfl_xor(sq, 1); sq += __shfl_xor(sq, 2);
    sq += __shfl_xor(sq, 4); sq += __shfl_xor(sq, 8);
    float sc = (sq / (1.f + sq)) / sqrtf(sq + 1e-8f);
    p_out[(size_t)(row0 + row) * 128 + col] = val * sc;
  }
}

// ---------------------------------------------------------------------------
// K2: Gram-based routing (verified round 4, unchanged).
// ---------------------------------------------------------------------------
__global__ __launch_bounds__(256, 1) void caps_route_g(
    const float* __restrict__ p_in, const float* __restrict__ Mg,
    float* __restrict__ qout)
{
  __shared__ float p_lds[128 * 66];
  __shared__ float M_lds[16384];
  __shared__ float G_lds[64 * 37];
  __shared__ float cs_lds[64 * 9];
  const int tid  = threadIdx.x;
  const int lane = tid & 63;
  const int w    = tid >> 6;
  const int row0 = blockIdx.x * 64;

#pragma unroll
  for (int i = 0; i < 8; ++i) {
    int j = tid + i * 256;
    int r = j >> 5, c4 = j & 31;
    float4 v = *(const float4*)(p_in + (size_t)(row0 + r) * 128 + c4 * 4);
    p_lds[(c4 * 4 + 0) * 66 + r] = v.x;
    p_lds[(c4 * 4 + 1) * 66 + r] = v.y;
    p_lds[(c4 * 4 + 2) * 66 + r] = v.z;
    p_lds[(c4 * 4 + 3) * 66 + r] = v.w;
  }
#pragma unroll
  for (int i = 0; i < 16; ++i) {
    int j = tid + i * 256;
    *(float4*)&M_lds[j * 4] = *(const float4*)(Mg + j * 4);
  }
  __syncthreads();

  for (int i = 0; i < 9; ++i) {
    const int pi = w * 9 + i;
    const int m = PM36[pi], n = PN36[pi];
    float pm[16], pn[16];
#pragma unroll
    for (int j = 0; j < 16; ++j) pm[j] = p_lds[(m * 16 + j) * 66 + lane];
#pragma unroll
    for (int j = 0; j < 16; ++j) pn[j] = p_lds[(n * 16 + j) * 66 + lane];
    float acc = 0.f;
#pragma unroll
    for (int ii = 0; ii < 16; ++ii) {
      const float* Mr = &M_lds[(n * 16 + ii) * 128 + m * 16];
      float t = 0.f;
#pragma unroll
      for (int j4 = 0; j4 < 4; ++j4) {
        float4 mv = *(const float4*)(Mr + j4 * 4);
        t = fmaf(mv.x, pm[j4 * 4 + 0], t);
        t = fmaf(mv.y, pm[j4 * 4 + 1], t);
        t = fmaf(mv.z, pm[j4 * 4 + 2], t);
        t = fmaf(mv.w, pm[j4 * 4 + 3], t);
      }
      acc = fmaf(pn[ii], t, acc);
    }
    G_lds[lane * 37 + pi] = acc;
  }
  __syncthreads();

  if (w == 0) {
    float Gf[36];
#pragma unroll
    for (int j = 0; j < 36; ++j) Gf[j] = G_lds[lane * 37 + j];
    float bb[8] = {0.f, 0.f, 0.f, 0.f, 0.f, 0.f, 0.f, 0.f};
    float cs[8];
#pragma unroll
    for (int it = 0; it < 3; ++it) {
      float mx = bb[0];
#pragma unroll
      for (int n = 1; n < 8; ++n) mx = fmaxf(mx, bb[n]);
      float e[8], Z = 0.f;
#pragma unroll
      for (int n = 0; n < 8; ++n) { e[n] = expf(bb[n] - mx); Z += e[n]; }
      float inv = 1.f / Z;
      float c[8];
#pragma unroll
      for (int n = 0; n < 8; ++n) c[n] = e[n] * inv;
      float t[8] = {0.f, 0.f, 0.f, 0.f, 0.f, 0.f, 0.f, 0.f};
#pragma unroll
      for (int n = 0; n < 8; ++n)
#pragma unroll
        for (int m2 = 0; m2 < 8; ++m2)
          t[n] = fmaf(Gf[gidx(n, m2)], c[m2], t[n]);
      float ss = 0.f;
#pragma unroll
      for (int n = 0; n < 8; ++n) ss = fmaf(c[n], t[n], ss);
      float scale = (ss / (1.f + ss)) / sqrtf(ss + 1e-8f);
      if (it < 2) {
#pragma unroll
        for (int n = 0; n < 8; ++n) bb[n] += scale * t[n];
      } else {
#pragma unroll
        for (int n = 0; n < 8; ++n) cs[n] = scale * c[n];
      }
    }
#pragma unroll
    for (int n = 0; n < 8; ++n) cs_lds[lane * 9 + n] = cs[n];
  }
  __syncthreads();

#pragma unroll
  for (int i = 0; i < 8; ++i) {
    int j = tid + i * 256;
    int r = j >> 5, c4 = j & 31;
    float4 pv = *(const float4*)(p_in + (size_t)(row0 + r) * 128 + c4 * 4);
    float csv = cs_lds[r * 9 + (c4 >> 2)];
    *(float4*)(qout + (size_t)(row0 + r) * 128 + c4 * 4) =
        make_float4(pv.x * csv, pv.y * csv, pv.z * csv, pv.w * csv);
  }
}

// ---------------------------------------------------------------------------
// K3: v = q @ Wflat  [16384,128]x[128,512] split-bf16 via 32x32x16 MFMA.
// A register-direct from q; B staged ONCE to 64 KB LDS (1 barrier).
// Block 512 thr (8 waves: wm=w>>2 rows, wn=w&3 cols), BM=64, BN=128,
// grid (256,4). Per wave: 24 MFMA(32x32x16), 16 ds_read_b128.
// ---------------------------------------------------------------------------
__global__ __launch_bounds__(512) void caps_vout(
    const float* __restrict__ q, const unsigned short* __restrict__ bth,
    const unsigned short* __restrict__ btl, float* __restrict__ out)
{
  __shared__ unsigned short Bsh[32768];   // hi @0, lo @16384 (ushorts)
  const int tid  = threadIdx.x;
  const int lane = tid & 63;
  const int w    = tid >> 6;
  const int wm   = w >> 2;         // 0..1 -> rows wm*32..+31
  const int wn   = w & 3;          // 0..3 -> cols wn*32..+31
  const int lc   = lane & 31;
  const int hi   = lane >> 5;
  const int row0 = blockIdx.x * 64;
  const int col0 = blockIdx.y * 128;

  // stage both K-tiles of B for this col-slab: [kt2][ks8][128col][e8]
#pragma unroll
  for (int i = 0; i < 4; ++i) {
    int idx = tid + i * 512;               // 2048 chunks
    int kt = idx >> 10, kg = (idx >> 7) & 7, col = idx & 127;
    size_t g = ((size_t)(kt * 8 + kg) * 512 + col0 + col) * 8;
    *(u16x8*)&Bsh[idx * 8] = *(const u16x8*)(bth + g);
    *(u16x8*)&Bsh[16384 + idx * 8] = *(const u16x8*)(btl + g);
  }
  __syncthreads();

  const float* qp = q + (size_t)(row0 + wm * 32 + lc) * 128;

  f32x16 acc;
#pragma unroll
  for (int j = 0; j < 16; ++j) acc[j] = 0.f;

#pragma unroll
  for (int kt = 0; kt < 2; ++kt) {
#pragma unroll
    for (int kk = 0; kk < 4; ++kk) {
      const float* qk = qp + kt * 64 + kk * 16 + hi * 8;
      float4 a0 = *(const float4*)(qk);
      float4 a1 = *(const float4*)(qk + 4);
      bf16x8 ah, al;
      cvt8b(a0, a1, ah, al);
      const int ks = kk * 2 + hi;
      const int fi = ((kt * 8 + ks) * 128 + wn * 32 + lc) * 8;
      bf16x8 bh  = *(const bf16x8*)&Bsh[fi];
      bf16x8 blo = *(const bf16x8*)&Bsh[16384 + fi];
      acc = MFMA32(ah, bh,  acc);
      acc = MFMA32(ah, blo, acc);
      acc = MFMA32(al, bh,  acc);
    }
  }

#pragma unroll
  for (int r = 0; r < 16; ++r) {
    const int row = (r & 3) + 8 * (r >> 2) + 4 * hi;
    out[(size_t)(row0 + wm * 32 + row) * 512 + col0 + wn * 32 + lc] = acc[r];
  }
}

extern "C" void kernel_launch(void* const* d_in, const int* in_sizes, int n_in,
                              void* d_out, int out_size, void* d_ws, size_t ws_size,
                              hipStream_t stream) {
  (void)in_sizes; (void)n_in; (void)out_size; (void)ws_size;
  const float* x  = (const float*)d_in[0];
  const float* Wp = (const float*)d_in[1];
  const float* bp = (const float*)d_in[2];
  const float* W  = (const float*)d_in[3];
  // d_in[4] = n_routing (fixed = 3)
  char* ws = (char*)d_ws;
  float* p_ws = (float*)ws;                                   // 8 MB (p, then q in-place)
  unsigned short* th1 = (unsigned short*)(ws + 8388608);      // 256 KB
  unsigned short* tl1 = (unsigned short*)(ws + 8650752);      // 256 KB
  unsigned short* th2 = (unsigned short*)(ws + 8912896);      // 128 KB
  unsigned short* tl2 = (unsigned short*)(ws + 9043968);      // 128 KB
  float* Mws = (float*)(ws + 9175040);                        // 64 KB
  float* outp = (float*)d_out;

  caps_prep_all<<<96, 256, 0, stream>>>(Wp, W, th1, tl1, th2, tl2, Mws);
  caps_primary<<<512, 256, 0, stream>>>(x, th1, tl1, bp, p_ws);
  caps_route_g<<<256, 256, 0, stream>>>(p_ws, Mws, p_ws);
  caps_vout<<<dim3(256, 4), 512, 0, stream>>>(p_ws, th2, tl2, outp);
}